// Round 6
// baseline (331.736 us; speedup 1.0000x reference)
//
#include <hip/hip_runtime.h>
#include <stdint.h>

#define NROWS 131072
#define DDIM  64
#define KCB   1024
#define BM    128          // rows per block (4 waves x 32)
#define NCHUNK 16          // K chunks of 64 cols

typedef short bf16x8 __attribute__((ext_vector_type(8)));
typedef float f32x4  __attribute__((ext_vector_type(4)));

__device__ __forceinline__ unsigned short f2bf(float f) {
    unsigned int u = __float_as_uint(f);
    u += 0x7FFFu + ((u >> 16) & 1u);
    return (unsigned short)(u >> 16);
}
__device__ __forceinline__ float bf2f(unsigned short h) {
    return __uint_as_float(((unsigned int)h) << 16);
}

// ---- pre-kernel: codebook -> bf16 hi/lo planes of (-2*c) + ||c||^2 (fp32) ----
// 4096 threads: each handles a 16-float quarter-row.
__global__ __launch_bounds__(256)
void convert_cb(const float* __restrict__ cb,
                unsigned short* __restrict__ mh,
                unsigned short* __restrict__ ml,
                float* __restrict__ csq) {
    const int t    = blockIdx.x * 256 + threadIdx.x;   // 0..4095
    const int row  = t >> 2;
    const int part = t & 3;
    const float4* src = (const float4*)(cb + (size_t)row * DDIM + part * 16);

    unsigned short hb[16], lb[16];
    float s = 0.f;
#pragma unroll
    for (int q = 0; q < 4; ++q) {
        float4 v = src[q];
        float c, m; unsigned short h;
        c = v.x; s = fmaf(c, c, s); m = -2.f * c; h = f2bf(m);
        hb[q*4+0] = h; lb[q*4+0] = f2bf(m - bf2f(h));
        c = v.y; s = fmaf(c, c, s); m = -2.f * c; h = f2bf(m);
        hb[q*4+1] = h; lb[q*4+1] = f2bf(m - bf2f(h));
        c = v.z; s = fmaf(c, c, s); m = -2.f * c; h = f2bf(m);
        hb[q*4+2] = h; lb[q*4+2] = f2bf(m - bf2f(h));
        c = v.w; s = fmaf(c, c, s); m = -2.f * c; h = f2bf(m);
        hb[q*4+3] = h; lb[q*4+3] = f2bf(m - bf2f(h));
    }
    s += __shfl_xor(s, 1);
    s += __shfl_xor(s, 2);
    if (part == 0) csq[row] = s;

    const size_t off = (size_t)row * DDIM + part * 16;
    short4* dh = (short4*)(mh + off);
    short4* dl = (short4*)(ml + off);
#pragma unroll
    for (int q = 0; q < 4; ++q) {
        short4 hv, lv;
        hv.x = (short)hb[q*4+0]; hv.y = (short)hb[q*4+1];
        hv.z = (short)hb[q*4+2]; hv.w = (short)hb[q*4+3];
        lv.x = (short)lb[q*4+0]; lv.y = (short)lb[q*4+1];
        lv.z = (short)lb[q*4+2]; lv.w = (short)lb[q*4+3];
        dh[q] = hv; dl[q] = lv;
    }
}

__device__ __forceinline__ void cvt8(float4 f0, float4 f1, bf16x8* h, bf16x8* l) {
    bf16x8 hh, ll;
    float fv; unsigned short hb;
    fv = f0.x; hb = f2bf(fv); hh[0] = (short)hb; ll[0] = (short)f2bf(fv - bf2f(hb));
    fv = f0.y; hb = f2bf(fv); hh[1] = (short)hb; ll[1] = (short)f2bf(fv - bf2f(hb));
    fv = f0.z; hb = f2bf(fv); hh[2] = (short)hb; ll[2] = (short)f2bf(fv - bf2f(hb));
    fv = f0.w; hb = f2bf(fv); hh[3] = (short)hb; ll[3] = (short)f2bf(fv - bf2f(hb));
    fv = f1.x; hb = f2bf(fv); hh[4] = (short)hb; ll[4] = (short)f2bf(fv - bf2f(hb));
    fv = f1.y; hb = f2bf(fv); hh[5] = (short)hb; ll[5] = (short)f2bf(fv - bf2f(hb));
    fv = f1.z; hb = f2bf(fv); hh[6] = (short)hb; ll[6] = (short)f2bf(fv - bf2f(hb));
    fv = f1.w; hb = f2bf(fv); hh[7] = (short)hb; ll[7] = (short)f2bf(fv - bf2f(hb));
    *h = hh; *l = ll;
}

__global__ __launch_bounds__(256, 3)
void codebook_mfma(const float* __restrict__ x,
                   const float* __restrict__ cb,
                   const unsigned short* __restrict__ cbh,   // bf16 hi of -2c
                   const unsigned short* __restrict__ cbl,   // bf16 lo of -2c
                   const float* __restrict__ csq,
                   float* __restrict__ out_codevec,
                   float* __restrict__ out_codes,
                   float* __restrict__ out_l2) {
    __shared__ float xs[BM][DDIM];     // fp32 x tile, kept for refinement
    __shared__ float xsq_s[BM];
    __shared__ int   cand_s[BM][2];

    const int tid  = threadIdx.x;
    const int lane = tid & 63;
    const int wid  = tid >> 6;
    const int row0 = blockIdx.x * BM;

    // ---- stage x (fp32, coalesced) + per-row ||x||^2 ----
    {
        const int r = tid >> 1, h = tid & 1;
        const float4* src = (const float4*)(x + (size_t)(row0 + r) * DDIM + h * 32);
        float4* dst = (float4*)&xs[r][h * 32];
        float s0 = 0.f, s1 = 0.f;
#pragma unroll
        for (int q = 0; q < 8; ++q) {
            float4 v = src[q];
            dst[q] = v;
            s0 = fmaf(v.x, v.x, s0); s0 = fmaf(v.y, v.y, s0);
            s1 = fmaf(v.z, v.z, s1); s1 = fmaf(v.w, v.w, s1);
        }
        float s = s0 + s1;
        s += __shfl_xor(s, 1);
        if (h == 0) xsq_s[r] = s;
    }
    __syncthreads();

    const int mrow = wid * 32;     // wave's first row within block
    const int cl   = lane & 15;
    const int ch   = lane >> 4;

    // ---- A fragments (x hi/lo), formed once; row=cl, k=ks*32+ch*8+j ----
    bf16x8 ah[2][2], al[2][2];
#pragma unroll
    for (int mt = 0; mt < 2; ++mt)
#pragma unroll
    for (int ks = 0; ks < 2; ++ks) {
        const float* p = &xs[mrow + mt * 16 + cl][ks * 32 + ch * 8];
        cvt8(*(const float4*)p, *(const float4*)(p + 4), &ah[mt][ks], &al[mt][ks]);
    }

    float xq[2][4];
#pragma unroll
    for (int mt = 0; mt < 2; ++mt)
#pragma unroll
    for (int rg = 0; rg < 4; ++rg)
        xq[mt][rg] = xsq_s[mrow + mt * 16 + ch * 4 + rg];

    float m1[2][4], m2[2][4];
    int   i1[2][4], i2[2][4];
#pragma unroll
    for (int mt = 0; mt < 2; ++mt)
#pragma unroll
    for (int rg = 0; rg < 4; ++rg) {
        m1[mt][rg] = 3.4e38f; m2[mt][rg] = 3.4e38f;
        i1[mt][rg] = 0;       i2[mt][rg] = 0;
    }

    // element offset of (mt=0, rg=0, chunk=0, nt=0) for this thread
    const uint32_t obase = (uint32_t)(row0 + mrow + ch * 4) * KCB + (uint32_t)cl;

#pragma unroll 2
    for (int chunk = 0; chunk < NCHUNK; ++chunk) {
        const int k0 = chunk << 6;
#pragma unroll
        for (int nt = 0; nt < 4; ++nt) {
            const int ncol = k0 + nt * 16 + cl;     // B col = codebook index
            const size_t bof = (size_t)ncol * DDIM + ch * 8;
            bf16x8 bh0 = *(const bf16x8*)(cbh + bof);
            bf16x8 bh1 = *(const bf16x8*)(cbh + bof + 32);
            bf16x8 bl0 = *(const bf16x8*)(cbl + bof);
            bf16x8 bl1 = *(const bf16x8*)(cbl + bof + 32);
            const float cq = csq[ncol];
#pragma unroll
            for (int mt = 0; mt < 2; ++mt) {
                // acc init = xsq + csq; MFMA adds -2*dot => acc = l2 directly
                f32x4 a;
                a[0] = xq[mt][0] + cq; a[1] = xq[mt][1] + cq;
                a[2] = xq[mt][2] + cq; a[3] = xq[mt][3] + cq;
                a = __builtin_amdgcn_mfma_f32_16x16x32_bf16(ah[mt][0], bh0, a, 0, 0, 0);
                a = __builtin_amdgcn_mfma_f32_16x16x32_bf16(ah[mt][1], bh1, a, 0, 0, 0);
                a = __builtin_amdgcn_mfma_f32_16x16x32_bf16(ah[mt][0], bl0, a, 0, 0, 0);
                a = __builtin_amdgcn_mfma_f32_16x16x32_bf16(ah[mt][1], bl1, a, 0, 0, 0);
                a = __builtin_amdgcn_mfma_f32_16x16x32_bf16(al[mt][0], bh0, a, 0, 0, 0);
                a = __builtin_amdgcn_mfma_f32_16x16x32_bf16(al[mt][1], bh1, a, 0, 0, 0);
#pragma unroll
                for (int rg = 0; rg < 4; ++rg) {
                    const float l2 = a[rg];
                    __builtin_nontemporal_store(
                        l2, out_l2 + obase + (uint32_t)((mt * 16 + rg) * KCB + k0 + nt * 16));
                    const bool c1 = l2 < m1[mt][rg];
                    const bool c2 = l2 < m2[mt][rg];
                    const float nm2 = c1 ? m1[mt][rg] : (c2 ? l2 : m2[mt][rg]);
                    const int   ni2 = c1 ? i1[mt][rg] : (c2 ? ncol : i2[mt][rg]);
                    m2[mt][rg] = nm2; i2[mt][rg] = ni2;
                    m1[mt][rg] = c1 ? l2 : m1[mt][rg];
                    i1[mt][rg] = c1 ? ncol : i1[mt][rg];
                }
            }
        }
    }

    // ---- top-2 butterfly across the 16 lanes sharing each row ----
#pragma unroll
    for (int mt = 0; mt < 2; ++mt)
#pragma unroll
    for (int rg = 0; rg < 4; ++rg) {
        float a1 = m1[mt][rg], a2 = m2[mt][rg];
        int   j1 = i1[mt][rg], j2 = i2[mt][rg];
#pragma unroll
        for (int mm = 1; mm < 16; mm <<= 1) {
            float o1 = __shfl_xor(a1, mm), o2 = __shfl_xor(a2, mm);
            int   q1 = __shfl_xor(j1, mm), q2 = __shfl_xor(j2, mm);
            const bool fw = (o1 < a1) || (o1 == a1 && q1 < j1);
            const float w1 = fw ? o1 : a1; const int wj1 = fw ? q1 : j1;
            const float ca = fw ? a1 : o1; const int cja = fw ? j1 : q1;
            const float cbv = fw ? o2 : a2; const int cjb = fw ? q2 : j2;
            const bool sw = (cbv < ca) || (cbv == ca && cjb < cja);
            a1 = w1; j1 = wj1;
            a2 = sw ? cbv : ca; j2 = sw ? cjb : cja;
        }
        if (cl == 0) {
            const int r = mrow + mt * 16 + ch * 4 + rg;
            cand_s[r][0] = j1; cand_s[r][1] = j2;
        }
    }
    __syncthreads();

    // ---- fp32 refinement of top-2, codes + code_vec ----
    {
        const int r = tid >> 1, h = tid & 1;
        const int cand = cand_s[r][h];
        const float4* xr = (const float4*)&xs[r][0];
        const float4* cr = (const float4*)(cb + (size_t)cand * DDIM);
        float s0 = 0.f, s1 = 0.f, s2 = 0.f, s3 = 0.f;
#pragma unroll
        for (int q = 0; q < 4; ++q) {
            float4 xa, ca;
            xa = xr[q];      ca = cr[q];
            s0 = fmaf(xa.x, ca.x, s0); s0 = fmaf(xa.y, ca.y, s0);
            s0 = fmaf(xa.z, ca.z, s0); s0 = fmaf(xa.w, ca.w, s0);
            xa = xr[q + 4];  ca = cr[q + 4];
            s1 = fmaf(xa.x, ca.x, s1); s1 = fmaf(xa.y, ca.y, s1);
            s1 = fmaf(xa.z, ca.z, s1); s1 = fmaf(xa.w, ca.w, s1);
            xa = xr[q + 8];  ca = cr[q + 8];
            s2 = fmaf(xa.x, ca.x, s2); s2 = fmaf(xa.y, ca.y, s2);
            s2 = fmaf(xa.z, ca.z, s2); s2 = fmaf(xa.w, ca.w, s2);
            xa = xr[q + 12]; ca = cr[q + 12];
            s3 = fmaf(xa.x, ca.x, s3); s3 = fmaf(xa.y, ca.y, s3);
            s3 = fmaf(xa.z, ca.z, s3); s3 = fmaf(xa.w, ca.w, s3);
        }
        const float dot = (s0 + s1) + (s2 + s3);
        const float d = fmaf(-2.f, dot, xsq_s[r] + csq[cand]);
        const float od = __shfl_xor(d, 1);
        const int   oc = __shfl_xor(cand, 1);
        const bool win = (d < od) || (d == od && cand < oc);
        const int w = win ? cand : oc;
        if (h == 0) out_codes[row0 + r] = (float)w;
        // nontemporal builtin requires clang vector types, not HIP float4
        const f32x4* wv = (const f32x4*)(cb + (size_t)w * DDIM + h * 32);
        f32x4* ov = (f32x4*)(out_codevec + (size_t)(row0 + r) * DDIM + h * 32);
#pragma unroll
        for (int q = 0; q < 8; ++q) __builtin_nontemporal_store(wv[q], ov + q);
    }
}

extern "C" void kernel_launch(void* const* d_in, const int* in_sizes, int n_in,
                              void* d_out, int out_size, void* d_ws, size_t ws_size,
                              hipStream_t stream) {
    (void)in_sizes; (void)n_in; (void)out_size; (void)ws_size;
    const float* x  = (const float*)d_in[0];
    const float* cb = (const float*)d_in[1];

    unsigned short* cbh = (unsigned short*)d_ws;                 // 128 KB
    unsigned short* cbl = cbh + (size_t)KCB * DDIM;              // 128 KB
    float*          csq = (float*)(cbl + (size_t)KCB * DDIM);    // 4 KB

    float* out_codevec = (float*)d_out;                          // N*D
    float* out_codes   = out_codevec + (size_t)NROWS * DDIM;     // N
    float* out_l2      = out_codes + NROWS;                      // N*K

    convert_cb<<<16, 256, 0, stream>>>(cb, cbh, cbl, csq);
    codebook_mfma<<<NROWS / BM, 256, 0, stream>>>(x, cb, cbh, cbl, csq,
                                                  out_codevec, out_codes, out_l2);
}

// Round 7
// 237.450 us; speedup vs baseline: 1.3971x; 1.3971x over previous
//
#include <hip/hip_runtime.h>
#include <stdint.h>

#define NROWS 131072
#define DDIM  64
#define KCB   1024
#define BM    128          // rows per block (4 waves x 32)
#define NCHUNK 16          // K chunks of 64 cols
#define XPAD  68           // padded LDS row stride (floats): 2-way banks = free

typedef short bf16x8 __attribute__((ext_vector_type(8)));
typedef float f32x4  __attribute__((ext_vector_type(4)));

__device__ __forceinline__ unsigned short f2bf(float f) {
    unsigned int u = __float_as_uint(f);
    u += 0x7FFFu + ((u >> 16) & 1u);
    return (unsigned short)(u >> 16);
}
__device__ __forceinline__ float bf2f(unsigned short h) {
    return __uint_as_float(((unsigned int)h) << 16);
}

// ---- pre-kernel: codebook -> bf16 hi/lo planes of (-2*c) + ||c||^2 (fp32) ----
__global__ __launch_bounds__(256)
void convert_cb(const float* __restrict__ cb,
                unsigned short* __restrict__ mh,
                unsigned short* __restrict__ ml,
                float* __restrict__ csq) {
    const int t    = blockIdx.x * 256 + threadIdx.x;   // 0..4095
    const int row  = t >> 2;
    const int part = t & 3;
    const float4* src = (const float4*)(cb + (size_t)row * DDIM + part * 16);

    unsigned short hb[16], lb[16];
    float s = 0.f;
#pragma unroll
    for (int q = 0; q < 4; ++q) {
        float4 v = src[q];
        float c, m; unsigned short h;
        c = v.x; s = fmaf(c, c, s); m = -2.f * c; h = f2bf(m);
        hb[q*4+0] = h; lb[q*4+0] = f2bf(m - bf2f(h));
        c = v.y; s = fmaf(c, c, s); m = -2.f * c; h = f2bf(m);
        hb[q*4+1] = h; lb[q*4+1] = f2bf(m - bf2f(h));
        c = v.z; s = fmaf(c, c, s); m = -2.f * c; h = f2bf(m);
        hb[q*4+2] = h; lb[q*4+2] = f2bf(m - bf2f(h));
        c = v.w; s = fmaf(c, c, s); m = -2.f * c; h = f2bf(m);
        hb[q*4+3] = h; lb[q*4+3] = f2bf(m - bf2f(h));
    }
    s += __shfl_xor(s, 1);
    s += __shfl_xor(s, 2);
    if (part == 0) csq[row] = s;

    const size_t off = (size_t)row * DDIM + part * 16;
    short4* dh = (short4*)(mh + off);
    short4* dl = (short4*)(ml + off);
#pragma unroll
    for (int q = 0; q < 4; ++q) {
        short4 hv, lv;
        hv.x = (short)hb[q*4+0]; hv.y = (short)hb[q*4+1];
        hv.z = (short)hb[q*4+2]; hv.w = (short)hb[q*4+3];
        lv.x = (short)lb[q*4+0]; lv.y = (short)lb[q*4+1];
        lv.z = (short)lb[q*4+2]; lv.w = (short)lb[q*4+3];
        dh[q] = hv; dl[q] = lv;
    }
}

__device__ __forceinline__ void cvt8(float4 f0, float4 f1, bf16x8* h, bf16x8* l) {
    bf16x8 hh, ll;
    float fv; unsigned short hb;
    fv = f0.x; hb = f2bf(fv); hh[0] = (short)hb; ll[0] = (short)f2bf(fv - bf2f(hb));
    fv = f0.y; hb = f2bf(fv); hh[1] = (short)hb; ll[1] = (short)f2bf(fv - bf2f(hb));
    fv = f0.z; hb = f2bf(fv); hh[2] = (short)hb; ll[2] = (short)f2bf(fv - bf2f(hb));
    fv = f0.w; hb = f2bf(fv); hh[3] = (short)hb; ll[3] = (short)f2bf(fv - bf2f(hb));
    fv = f1.x; hb = f2bf(fv); hh[4] = (short)hb; ll[4] = (short)f2bf(fv - bf2f(hb));
    fv = f1.y; hb = f2bf(fv); hh[5] = (short)hb; ll[5] = (short)f2bf(fv - bf2f(hb));
    fv = f1.z; hb = f2bf(fv); hh[6] = (short)hb; ll[6] = (short)f2bf(fv - bf2f(hb));
    fv = f1.w; hb = f2bf(fv); hh[7] = (short)hb; ll[7] = (short)f2bf(fv - bf2f(hb));
    *h = hh; *l = ll;
}

__global__ __launch_bounds__(256, 3)
void codebook_mfma(const float* __restrict__ x,
                   const float* __restrict__ cb,
                   const unsigned short* __restrict__ cbh,   // bf16 hi of -2c
                   const unsigned short* __restrict__ cbl,   // bf16 lo of -2c
                   const float* __restrict__ csq,
                   float* __restrict__ out_codevec,
                   float* __restrict__ out_codes,
                   float* __restrict__ out_l2) {
    __shared__ float xs[BM][XPAD];     // fp32 x tile (padded), kept for refinement
    __shared__ float tb[4][16][XPAD];  // per-wave store-transpose buffer
    __shared__ float xsq_s[BM];
    __shared__ int   cand_s[BM][2];

    const int tid  = threadIdx.x;
    const int lane = tid & 63;
    const int wid  = tid >> 6;
    const int row0 = blockIdx.x * BM;

    // ---- stage x (fp32, coalesced) + per-row ||x||^2 ----
    {
        const int r = tid >> 1, h = tid & 1;
        const float4* src = (const float4*)(x + (size_t)(row0 + r) * DDIM + h * 32);
        float4* dst = (float4*)&xs[r][h * 32];
        float s0 = 0.f, s1 = 0.f;
#pragma unroll
        for (int q = 0; q < 8; ++q) {
            float4 v = src[q];
            dst[q] = v;
            s0 = fmaf(v.x, v.x, s0); s0 = fmaf(v.y, v.y, s0);
            s1 = fmaf(v.z, v.z, s1); s1 = fmaf(v.w, v.w, s1);
        }
        float s = s0 + s1;
        s += __shfl_xor(s, 1);
        if (h == 0) xsq_s[r] = s;
    }
    __syncthreads();

    const int mrow = wid * 32;     // wave's first row within block
    const int cl   = lane & 15;
    const int ch   = lane >> 4;

    // ---- A fragments (x hi/lo), formed once; row=cl, k=ks*32+ch*8+j ----
    bf16x8 ah[2][2], al[2][2];
#pragma unroll
    for (int mt = 0; mt < 2; ++mt)
#pragma unroll
    for (int ks = 0; ks < 2; ++ks) {
        const float* p = &xs[mrow + mt * 16 + cl][ks * 32 + ch * 8];
        cvt8(*(const float4*)p, *(const float4*)(p + 4), &ah[mt][ks], &al[mt][ks]);
    }

    float xq[2][4];
#pragma unroll
    for (int mt = 0; mt < 2; ++mt)
#pragma unroll
    for (int rg = 0; rg < 4; ++rg)
        xq[mt][rg] = xsq_s[mrow + mt * 16 + ch * 4 + rg];

    float m1[2][4], m2[2][4];
    int   i1[2][4], i2[2][4];
#pragma unroll
    for (int mt = 0; mt < 2; ++mt)
#pragma unroll
    for (int rg = 0; rg < 4; ++rg) {
        m1[mt][rg] = 3.4e38f; m2[mt][rg] = 3.4e38f;
        i1[mt][rg] = 0;       i2[mt][rg] = 0;
    }

    for (int chunk = 0; chunk < NCHUNK; ++chunk) {
        const int k0 = chunk << 6;

        // ---- batched B loads for all 4 nt: one latency exposure per chunk ----
        bf16x8 vbh0[4], vbh1[4], vbl0[4], vbl1[4];
        float  cq[4];
#pragma unroll
        for (int nt = 0; nt < 4; ++nt) {
            const int ncol = k0 + nt * 16 + cl;
            const size_t bof = (size_t)ncol * DDIM + ch * 8;
            vbh0[nt] = *(const bf16x8*)(cbh + bof);
            vbh1[nt] = *(const bf16x8*)(cbh + bof + 32);
            vbl0[nt] = *(const bf16x8*)(cbl + bof);
            vbl1[nt] = *(const bf16x8*)(cbl + bof + 32);
            cq[nt]   = csq[ncol];
        }

#pragma unroll
        for (int mt = 0; mt < 2; ++mt) {
#pragma unroll
            for (int nt = 0; nt < 4; ++nt) {
                const int ncol = k0 + nt * 16 + cl;
                // acc init = xsq + csq; MFMA adds -2*dot => acc = l2 directly
                f32x4 a;
                a[0] = xq[mt][0] + cq[nt]; a[1] = xq[mt][1] + cq[nt];
                a[2] = xq[mt][2] + cq[nt]; a[3] = xq[mt][3] + cq[nt];
                a = __builtin_amdgcn_mfma_f32_16x16x32_bf16(ah[mt][0], vbh0[nt], a, 0, 0, 0);
                a = __builtin_amdgcn_mfma_f32_16x16x32_bf16(ah[mt][1], vbh1[nt], a, 0, 0, 0);
                a = __builtin_amdgcn_mfma_f32_16x16x32_bf16(ah[mt][0], vbl0[nt], a, 0, 0, 0);
                a = __builtin_amdgcn_mfma_f32_16x16x32_bf16(ah[mt][1], vbl1[nt], a, 0, 0, 0);
                a = __builtin_amdgcn_mfma_f32_16x16x32_bf16(al[mt][0], vbh0[nt], a, 0, 0, 0);
                a = __builtin_amdgcn_mfma_f32_16x16x32_bf16(al[mt][1], vbh1[nt], a, 0, 0, 0);
#pragma unroll
                for (int rg = 0; rg < 4; ++rg) {
                    const float l2 = a[rg];
                    tb[wid][ch * 4 + rg][nt * 16 + cl] = l2;   // scatter (2-way = free)
                    const bool c1 = l2 < m1[mt][rg];
                    const bool c2 = l2 < m2[mt][rg];
                    const float nm2 = c1 ? m1[mt][rg] : (c2 ? l2 : m2[mt][rg]);
                    const int   ni2 = c1 ? i1[mt][rg] : (c2 ? ncol : i2[mt][rg]);
                    m2[mt][rg] = nm2; i2[mt][rg] = ni2;
                    m1[mt][rg] = c1 ? l2 : m1[mt][rg];
                    i1[mt][rg] = c1 ? ncol : i1[mt][rg];
                }
            }
            // wave-local transpose read -> full-line coalesced nt stores
            asm volatile("s_waitcnt lgkmcnt(0)" ::: "memory");
#pragma unroll
            for (int s = 0; s < 4; ++s) {
                const f32x4 v = *(const f32x4*)&tb[wid][s * 4 + ch][cl * 4];
                f32x4* dst = (f32x4*)(out_l2 +
                    (size_t)(row0 + mrow + mt * 16 + s * 4 + ch) * KCB + k0 + cl * 4);
                __builtin_nontemporal_store(v, dst);
            }
        }
    }

    // ---- top-2 butterfly across the 16 lanes sharing each row ----
#pragma unroll
    for (int mt = 0; mt < 2; ++mt)
#pragma unroll
    for (int rg = 0; rg < 4; ++rg) {
        float a1 = m1[mt][rg], a2 = m2[mt][rg];
        int   j1 = i1[mt][rg], j2 = i2[mt][rg];
#pragma unroll
        for (int mm = 1; mm < 16; mm <<= 1) {
            float o1 = __shfl_xor(a1, mm), o2 = __shfl_xor(a2, mm);
            int   q1 = __shfl_xor(j1, mm), q2 = __shfl_xor(j2, mm);
            const bool fw = (o1 < a1) || (o1 == a1 && q1 < j1);
            const float w1 = fw ? o1 : a1; const int wj1 = fw ? q1 : j1;
            const float ca = fw ? a1 : o1; const int cja = fw ? j1 : q1;
            const float cbv = fw ? o2 : a2; const int cjb = fw ? q2 : j2;
            const bool sw = (cbv < ca) || (cbv == ca && cjb < cja);
            a1 = w1; j1 = wj1;
            a2 = sw ? cbv : ca; j2 = sw ? cjb : cja;
        }
        if (cl == 0) {
            const int r = mrow + mt * 16 + ch * 4 + rg;
            cand_s[r][0] = j1; cand_s[r][1] = j2;
        }
    }
    __syncthreads();

    // ---- fp32 refinement of top-2, codes + code_vec ----
    {
        const int r = tid >> 1, h = tid & 1;
        const int cand = cand_s[r][h];
        const float4* xr = (const float4*)&xs[r][0];
        const float4* cr = (const float4*)(cb + (size_t)cand * DDIM);
        float s0 = 0.f, s1 = 0.f, s2 = 0.f, s3 = 0.f;
#pragma unroll
        for (int q = 0; q < 4; ++q) {
            float4 xa, ca;
            xa = xr[q];      ca = cr[q];
            s0 = fmaf(xa.x, ca.x, s0); s0 = fmaf(xa.y, ca.y, s0);
            s0 = fmaf(xa.z, ca.z, s0); s0 = fmaf(xa.w, ca.w, s0);
            xa = xr[q + 4];  ca = cr[q + 4];
            s1 = fmaf(xa.x, ca.x, s1); s1 = fmaf(xa.y, ca.y, s1);
            s1 = fmaf(xa.z, ca.z, s1); s1 = fmaf(xa.w, ca.w, s1);
            xa = xr[q + 8];  ca = cr[q + 8];
            s2 = fmaf(xa.x, ca.x, s2); s2 = fmaf(xa.y, ca.y, s2);
            s2 = fmaf(xa.z, ca.z, s2); s2 = fmaf(xa.w, ca.w, s2);
            xa = xr[q + 12]; ca = cr[q + 12];
            s3 = fmaf(xa.x, ca.x, s3); s3 = fmaf(xa.y, ca.y, s3);
            s3 = fmaf(xa.z, ca.z, s3); s3 = fmaf(xa.w, ca.w, s3);
        }
        const float dot = (s0 + s1) + (s2 + s3);
        const float d = fmaf(-2.f, dot, xsq_s[r] + csq[cand]);
        const float od = __shfl_xor(d, 1);
        const int   oc = __shfl_xor(cand, 1);
        const bool win = (d < od) || (d == od && cand < oc);
        const int w = win ? cand : oc;
        if (h == 0) out_codes[row0 + r] = (float)w;
        const f32x4* wv = (const f32x4*)(cb + (size_t)w * DDIM + h * 32);
        f32x4* ov = (f32x4*)(out_codevec + (size_t)(row0 + r) * DDIM + h * 32);
#pragma unroll
        for (int q = 0; q < 8; ++q) __builtin_nontemporal_store(wv[q], ov + q);
    }
}

extern "C" void kernel_launch(void* const* d_in, const int* in_sizes, int n_in,
                              void* d_out, int out_size, void* d_ws, size_t ws_size,
                              hipStream_t stream) {
    (void)in_sizes; (void)n_in; (void)out_size; (void)ws_size;
    const float* x  = (const float*)d_in[0];
    const float* cb = (const float*)d_in[1];

    unsigned short* cbh = (unsigned short*)d_ws;                 // 128 KB
    unsigned short* cbl = cbh + (size_t)KCB * DDIM;              // 128 KB
    float*          csq = (float*)(cbl + (size_t)KCB * DDIM);    // 4 KB

    float* out_codevec = (float*)d_out;                          // N*D
    float* out_codes   = out_codevec + (size_t)NROWS * DDIM;     // N
    float* out_l2      = out_codes + NROWS;                      // N*K

    convert_cb<<<16, 256, 0, stream>>>(cb, cbh, cbl, csq);
    codebook_mfma<<<NROWS / BM, 256, 0, stream>>>(x, cb, cbh, cbl, csq,
                                                  out_codevec, out_codes, out_l2);
}